// Round 1
// baseline (1712.458 us; speedup 1.0000x reference)
//
#include <hip/hip_runtime.h>
#include <math.h>

#define BS   8
#define CIN  512
#define HC_  64
#define C2   256
#define NPIX 4096
#define WAO  384

// ---------------- Kernel A: w = Wa @ inputs (per-pixel 1x1 conv) ----------------
// grid (64 n-tiles, 3 o-tiles, 8 batch), block 256. Tile 128o x 64n, K-chunk 32.
__global__ __launch_bounds__(256) void k_proj_a(
    const float* __restrict__ inp, const float* __restrict__ Wa,
    float* __restrict__ w_buf)
{
    __shared__ float wa_s[32][132];
    __shared__ float in_s[32][68];
    const int b  = blockIdx.z;
    const int o0 = blockIdx.y * 128;
    const int n0 = blockIdx.x * 64;
    const int t  = threadIdx.x;
    const int to = t >> 4, tn = t & 15;
    float acc[8][4];
#pragma unroll
    for (int i = 0; i < 8; ++i)
#pragma unroll
        for (int j = 0; j < 4; ++j) acc[i][j] = 0.f;

    for (int i0 = 0; i0 < CIN; i0 += 32) {
#pragma unroll
        for (int jj = 0; jj < 4; ++jj) {
            const int row = (t >> 3) + 32 * jj;
            const int col = (t & 7) << 2;
            const float4 v = *reinterpret_cast<const float4*>(
                &Wa[(size_t)(o0 + row) * CIN + i0 + col]);
            wa_s[col + 0][row] = v.x; wa_s[col + 1][row] = v.y;
            wa_s[col + 2][row] = v.z; wa_s[col + 3][row] = v.w;
        }
#pragma unroll
        for (int jj = 0; jj < 2; ++jj) {
            const int ii = (t >> 4) + 16 * jj;
            const int nn = (t & 15) << 2;
            *reinterpret_cast<float4*>(&in_s[ii][nn]) =
                *reinterpret_cast<const float4*>(
                    &inp[((size_t)b * CIN + i0 + ii) * NPIX + n0 + nn]);
        }
        __syncthreads();
#pragma unroll
        for (int kc = 0; kc < 32; ++kc) {
            const float4 a0 = *reinterpret_cast<const float4*>(&wa_s[kc][to * 8]);
            const float4 a1 = *reinterpret_cast<const float4*>(&wa_s[kc][to * 8 + 4]);
            const float4 x0 = *reinterpret_cast<const float4*>(&in_s[kc][tn * 4]);
            const float a[8] = {a0.x, a0.y, a0.z, a0.w, a1.x, a1.y, a1.z, a1.w};
            const float x[4] = {x0.x, x0.y, x0.z, x0.w};
#pragma unroll
            for (int i = 0; i < 8; ++i)
#pragma unroll
                for (int j = 0; j < 4; ++j) acc[i][j] = fmaf(a[i], x[j], acc[i][j]);
        }
        __syncthreads();
    }
#pragma unroll
    for (int i = 0; i < 8; ++i) {
        *reinterpret_cast<float4*>(
            &w_buf[((size_t)b * WAO + o0 + to * 8 + i) * NPIX + n0 + tn * 4]) =
            make_float4(acc[i][0], acc[i][1], acc[i][2], acc[i][3]);
    }
}

// ---------------- Kernel B: flash attention (fp32) ----------------
// grid (64 q-tiles, 8 batch), block 256. Q-tile 64 rows, m-tile 32.
__global__ __launch_bounds__(256) void k_attn(
    const float* __restrict__ w_buf, float* __restrict__ y_buf)
{
    __shared__ float qs[64][64];    // [c][r]
    __shared__ float ks[64][34];    // [c][m]
    __shared__ float vs[32][260];   // [m][c]
    __shared__ float ps[32][68];    // [m][r]
    __shared__ float mrow[64], lsum[64], resc[64];

    const int b  = blockIdx.y;
    const int n0 = blockIdx.x * 64;
    const int t  = threadIdx.x;
    const float* qg = w_buf + (size_t)b * WAO * NPIX;
    const float* kg = qg + (size_t)HC_ * NPIX;
    const float* vg = qg + (size_t)2 * HC_ * NPIX;

    {
        const int r4 = (t & 15) << 2;
#pragma unroll
        for (int j = 0; j < 4; ++j) {
            const int c = (t >> 4) + 16 * j;
            const float4 v = *reinterpret_cast<const float4*>(
                &qg[(size_t)c * NPIX + n0 + r4]);
            qs[c][r4 + 0] = v.x; qs[c][r4 + 1] = v.y;
            qs[c][r4 + 2] = v.z; qs[c][r4 + 3] = v.w;
        }
    }
    if (t < 64) { mrow[t] = -INFINITY; lsum[t] = 0.f; resc[t] = 0.f; }

    float yacc[8][8];
#pragma unroll
    for (int i = 0; i < 8; ++i)
#pragma unroll
        for (int j = 0; j < 8; ++j) yacc[i][j] = 0.f;

    const int tc = t >> 3, tr = t & 7;      // y-update: 8c x 8r micro-tile
    const int sr = t & 15, sm = t >> 4;     // S-comp: 4r x 2m micro-tile
    const int row = t >> 2, part = t & 3;   // stats: 4 threads per row

    __syncthreads();

    for (int m0 = 0; m0 < NPIX; m0 += 32) {
        {   // stage K [64c x 32m] and V [32m x 256c] tiles
            const int mm = (t & 7) << 2;
            const int cb = t >> 3;
#pragma unroll
            for (int j = 0; j < 2; ++j) {
                const int c = cb + 32 * j;
                const float4 v = *reinterpret_cast<const float4*>(
                    &kg[(size_t)c * NPIX + m0 + mm]);
                ks[c][mm + 0] = v.x; ks[c][mm + 1] = v.y;
                ks[c][mm + 2] = v.z; ks[c][mm + 3] = v.w;
            }
#pragma unroll
            for (int j = 0; j < 8; ++j) {
                const int c = cb + 32 * j;
                const float4 v = *reinterpret_cast<const float4*>(
                    &vg[(size_t)c * NPIX + m0 + mm]);
                vs[mm + 0][c] = v.x; vs[mm + 1][c] = v.y;
                vs[mm + 2][c] = v.z; vs[mm + 3][c] = v.w;
            }
        }
        __syncthreads();
        {   // S = Q^T K  (4 rows x 2 m per thread)
            float s[4][2] = {{0.f, 0.f}, {0.f, 0.f}, {0.f, 0.f}, {0.f, 0.f}};
#pragma unroll
            for (int c = 0; c < 64; ++c) {
                const float4 q4 = *reinterpret_cast<const float4*>(&qs[c][sr * 4]);
                const float2 k2 = *reinterpret_cast<const float2*>(&ks[c][sm * 2]);
                s[0][0] = fmaf(q4.x, k2.x, s[0][0]); s[0][1] = fmaf(q4.x, k2.y, s[0][1]);
                s[1][0] = fmaf(q4.y, k2.x, s[1][0]); s[1][1] = fmaf(q4.y, k2.y, s[1][1]);
                s[2][0] = fmaf(q4.z, k2.x, s[2][0]); s[2][1] = fmaf(q4.z, k2.y, s[2][1]);
                s[3][0] = fmaf(q4.w, k2.x, s[3][0]); s[3][1] = fmaf(q4.w, k2.y, s[3][1]);
            }
#pragma unroll
            for (int e = 0; e < 4; ++e) {
                ps[sm * 2 + 0][sr * 4 + e] = s[e][0];
                ps[sm * 2 + 1][sr * 4 + e] = s[e][1];
            }
        }
        __syncthreads();
        {   // online softmax stats; overwrite ps with exp(s - m_new)
            float sv[8];
            float mx = -INFINITY;
#pragma unroll
            for (int k = 0; k < 8; ++k) {
                sv[k] = ps[part * 8 + k][row];
                mx = fmaxf(mx, sv[k]);
            }
            mx = fmaxf(mx, __shfl_xor(mx, 1, 4));
            mx = fmaxf(mx, __shfl_xor(mx, 2, 4));
            const float mold = mrow[row];
            const float mnew = fmaxf(mold, mx);
            const float rs   = __expf(mold - mnew);
            float ll = 0.f;
#pragma unroll
            for (int k = 0; k < 8; ++k) {
                const float p = __expf(sv[k] - mnew);
                ps[part * 8 + k][row] = p;
                ll += p;
            }
            ll += __shfl_xor(ll, 1, 4);
            ll += __shfl_xor(ll, 2, 4);
            if (part == 0) {
                lsum[row] = lsum[row] * rs + ll;
                mrow[row] = mnew;
                resc[row] = rs;
            }
        }
        __syncthreads();
        {   // y += P V  (8c x 8r per thread), with rescale
            float rsv[8];
#pragma unroll
            for (int e = 0; e < 8; ++e) rsv[e] = resc[tr * 8 + e];
#pragma unroll
            for (int cf = 0; cf < 8; ++cf)
#pragma unroll
                for (int e = 0; e < 8; ++e) yacc[cf][e] *= rsv[e];
#pragma unroll
            for (int m = 0; m < 32; ++m) {
                const float4 p0 = *reinterpret_cast<const float4*>(&ps[m][tr * 8]);
                const float4 p1 = *reinterpret_cast<const float4*>(&ps[m][tr * 8 + 4]);
                const float4 v0 = *reinterpret_cast<const float4*>(&vs[m][tc * 8]);
                const float4 v1 = *reinterpret_cast<const float4*>(&vs[m][tc * 8 + 4]);
                const float pv[8] = {p0.x, p0.y, p0.z, p0.w, p1.x, p1.y, p1.z, p1.w};
                const float vv[8] = {v0.x, v0.y, v0.z, v0.w, v1.x, v1.y, v1.z, v1.w};
#pragma unroll
                for (int cf = 0; cf < 8; ++cf)
#pragma unroll
                    for (int e = 0; e < 8; ++e)
                        yacc[cf][e] = fmaf(vv[cf], pv[e], yacc[cf][e]);
            }
        }
        __syncthreads();
    }
    float il[8];
#pragma unroll
    for (int e = 0; e < 8; ++e) il[e] = 1.f / lsum[tr * 8 + e];
#pragma unroll
    for (int cf = 0; cf < 8; ++cf) {
        float o[8];
#pragma unroll
        for (int e = 0; e < 8; ++e) o[e] = yacc[cf][e] * il[e];
        float* dst = &y_buf[((size_t)b * C2 + tc * 8 + cf) * NPIX + n0 + tr * 8];
        *reinterpret_cast<float4*>(dst)     = make_float4(o[0], o[1], o[2], o[3]);
        *reinterpret_cast<float4*>(dst + 4) = make_float4(o[4], o[5], o[6], o[7]);
    }
}

// ---------------- Kernel C: out = gamma * (Wo @ y) + inputs ----------------
// grid (64 n-tiles, 4 j-tiles, 8 batch), block 256. Tile 128j x 64n, K-chunk 32.
__global__ __launch_bounds__(256) void k_proj_o(
    const float* __restrict__ y_buf, const float* __restrict__ Wo,
    const float* __restrict__ inp, const float* __restrict__ gamma,
    float* __restrict__ out)
{
    __shared__ float wo_s[32][132];
    __shared__ float y_s[32][68];
    const int b  = blockIdx.z;
    const int j0 = blockIdx.y * 128;
    const int n0 = blockIdx.x * 64;
    const int t  = threadIdx.x;
    const int to = t >> 4, tn = t & 15;
    float acc[8][4];
#pragma unroll
    for (int i = 0; i < 8; ++i)
#pragma unroll
        for (int j = 0; j < 4; ++j) acc[i][j] = 0.f;

    for (int i0 = 0; i0 < C2; i0 += 32) {
#pragma unroll
        for (int jj = 0; jj < 4; ++jj) {
            const int row = (t >> 3) + 32 * jj;
            const int col = (t & 7) << 2;
            const float4 v = *reinterpret_cast<const float4*>(
                &Wo[(size_t)(j0 + row) * C2 + i0 + col]);
            wo_s[col + 0][row] = v.x; wo_s[col + 1][row] = v.y;
            wo_s[col + 2][row] = v.z; wo_s[col + 3][row] = v.w;
        }
#pragma unroll
        for (int jj = 0; jj < 2; ++jj) {
            const int ii = (t >> 4) + 16 * jj;
            const int nn = (t & 15) << 2;
            *reinterpret_cast<float4*>(&y_s[ii][nn]) =
                *reinterpret_cast<const float4*>(
                    &y_buf[((size_t)b * C2 + i0 + ii) * NPIX + n0 + nn]);
        }
        __syncthreads();
#pragma unroll
        for (int kc = 0; kc < 32; ++kc) {
            const float4 a0 = *reinterpret_cast<const float4*>(&wo_s[kc][to * 8]);
            const float4 a1 = *reinterpret_cast<const float4*>(&wo_s[kc][to * 8 + 4]);
            const float4 x0 = *reinterpret_cast<const float4*>(&y_s[kc][tn * 4]);
            const float a[8] = {a0.x, a0.y, a0.z, a0.w, a1.x, a1.y, a1.z, a1.w};
            const float x[4] = {x0.x, x0.y, x0.z, x0.w};
#pragma unroll
            for (int i = 0; i < 8; ++i)
#pragma unroll
                for (int j = 0; j < 4; ++j) acc[i][j] = fmaf(a[i], x[j], acc[i][j]);
        }
        __syncthreads();
    }
    const float g = gamma[0];
#pragma unroll
    for (int i = 0; i < 8; ++i) {
        const size_t idx = ((size_t)b * CIN + j0 + to * 8 + i) * NPIX + n0 + tn * 4;
        const float4 r = *reinterpret_cast<const float4*>(&inp[idx]);
        *reinterpret_cast<float4*>(&out[idx]) =
            make_float4(fmaf(g, acc[i][0], r.x), fmaf(g, acc[i][1], r.y),
                        fmaf(g, acc[i][2], r.z), fmaf(g, acc[i][3], r.w));
    }
}

extern "C" void kernel_launch(void* const* d_in, const int* in_sizes, int n_in,
                              void* d_out, int out_size, void* d_ws, size_t ws_size,
                              hipStream_t stream) {
    const float* inputs = (const float*)d_in[0];
    const float* Wa     = (const float*)d_in[1];
    const float* Wo     = (const float*)d_in[2];
    const float* gamma  = (const float*)d_in[3];
    float* out = (float*)d_out;

    const size_t w_elems = (size_t)BS * WAO * NPIX;   // 12.6M floats (48 MB)
    const size_t y_elems = (size_t)BS * C2 * NPIX;    // 8.4M floats (32 MB)

    float* w_buf;
    float* y_buf;
    if (ws_size >= (w_elems + y_elems) * sizeof(float)) {
        w_buf = (float*)d_ws;
        y_buf = w_buf + w_elems;
    } else {
        // fallback: stage w in d_out (64 MB >= 48 MB); it is fully consumed by
        // k_attn before k_proj_o overwrites d_out with the final result.
        w_buf = out;
        y_buf = (float*)d_ws;
    }

    k_proj_a<<<dim3(64, 3, 8), 256, 0, stream>>>(inputs, Wa, w_buf);
    k_attn  <<<dim3(64, 8),    256, 0, stream>>>(w_buf, y_buf);
    k_proj_o<<<dim3(64, 4, 8), 256, 0, stream>>>(y_buf, Wo, inputs, gamma, out);
}

// Round 2
// 1024.337 us; speedup vs baseline: 1.6718x; 1.6718x over previous
//
#include <hip/hip_runtime.h>
#include <math.h>

#define BS   8
#define CIN  512
#define HC_  64
#define C2   256
#define NPIX 4096
#define WAO  384

typedef __attribute__((ext_vector_type(8))) short short8;
typedef __attribute__((ext_vector_type(4))) float f32x4;

__device__ __forceinline__ ushort f2bf(float f) {
    union { float f; unsigned int u; } v; v.f = f;
    return (ushort)((v.u + 0x7FFFu + ((v.u >> 16) & 1u)) >> 16);
}

#define MFMA16(a, b, c) __builtin_amdgcn_mfma_f32_16x16x32_bf16((a), (b), (c), 0, 0, 0)

// ---------------------------------------------------------------------------
// Kernel A: w = Wa @ inputs (1x1 conv), MFMA bf16.
// Writes qt[b][n][64] bf16, kt[b][m][64] bf16 (transposed: attn A/B want
// channel-contiguous), vb[b][c][m] bf16 (natural).
// grid (64 n-tiles, 3 o-tiles, 8 batch), block 256 (4 waves).
// Block tile: 128 o x 64 n. Wave: 128 o x 16 n. K-step 32.
// ---------------------------------------------------------------------------
__global__ __launch_bounds__(256) void k_proj_a(
    const float* __restrict__ inp, const float* __restrict__ Wa,
    ushort* __restrict__ qt, ushort* __restrict__ kt, ushort* __restrict__ vb)
{
    __shared__ ushort it[64][40];   // [n][c] bf16, stride 40 (80B, 16B-aligned, conflict-free b128)
    const int b  = blockIdx.z;
    const int o0 = blockIdx.y * 128;
    const int n0 = blockIdx.x * 64;
    const int t    = threadIdx.x;
    const int wave = t >> 6, lane = t & 63;
    const int ln   = lane & 15, gr = lane >> 4;
    const int wn   = wave * 16;

    f32x4 acc[8];
#pragma unroll
    for (int i = 0; i < 8; ++i) acc[i] = (f32x4){0.f, 0.f, 0.f, 0.f};

    const int sc = t >> 4;          // 0..15
    const int sn = (t & 15) * 4;    // 0..60

    for (int ks = 0; ks < 16; ++ks) {
        const int c0 = ks * 32;
        __syncthreads();   // protect `it` from previous iteration's readers
#pragma unroll
        for (int q = 0; q < 2; ++q) {
            const int c = sc + 16 * q;
            const float4 v = *(const float4*)&inp[((size_t)b * CIN + c0 + c) * NPIX + n0 + sn];
            it[sn + 0][c] = f2bf(v.x); it[sn + 1][c] = f2bf(v.y);
            it[sn + 2][c] = f2bf(v.z); it[sn + 3][c] = f2bf(v.w);
        }
        __syncthreads();
        const short8 bf = *(const short8*)&it[wn + ln][gr * 8];
#pragma unroll
        for (int ot = 0; ot < 8; ++ot) {
            const int row = o0 + ot * 16 + ln;
            const float4 w0 = *(const float4*)&Wa[(size_t)row * CIN + c0 + gr * 8];
            const float4 w1 = *(const float4*)&Wa[(size_t)row * CIN + c0 + gr * 8 + 4];
            short8 af;
            af[0] = (short)f2bf(w0.x); af[1] = (short)f2bf(w0.y);
            af[2] = (short)f2bf(w0.z); af[3] = (short)f2bf(w0.w);
            af[4] = (short)f2bf(w1.x); af[5] = (short)f2bf(w1.y);
            af[6] = (short)f2bf(w1.z); af[7] = (short)f2bf(w1.w);
            acc[ot] = MFMA16(af, bf, acc[ot]);
        }
    }

    // C-write. Lane holds w[o = ot*16 + 4*gr + r][n = n0 + wn + ln].
    const int n = n0 + wn + ln;
    if (o0 == 0) {
        // o in [0,128): q (0..63) and k (64..127), write transposed [n][c], 4 consecutive c packed.
#pragma unroll
        for (int ot = 0; ot < 8; ++ot) {
            const ushort b0 = f2bf(acc[ot][0]), b1 = f2bf(acc[ot][1]);
            const ushort b2 = f2bf(acc[ot][2]), b3 = f2bf(acc[ot][3]);
            uint2 pk;
            pk.x = (unsigned int)b0 | ((unsigned int)b1 << 16);
            pk.y = (unsigned int)b2 | ((unsigned int)b3 << 16);
            ushort* base = (ot < 4) ? qt : kt;
            const int c4 = (ot & 3) * 16 + 4 * gr;
            *(uint2*)&base[((size_t)b * NPIX + n) * 64 + c4] = pk;
        }
    } else {
        // o in [128,384): v channels, natural [c][m] layout.
#pragma unroll
        for (int ot = 0; ot < 8; ++ot) {
            const int cb = o0 - 128 + ot * 16 + 4 * gr;
#pragma unroll
            for (int r = 0; r < 4; ++r)
                vb[((size_t)b * C2 + cb + r) * NPIX + n] = f2bf(acc[ot][r]);
        }
    }
}

// ---------------------------------------------------------------------------
// Kernel B: flash attention, bf16 MFMA, fp32 softmax/accum.
// grid (64 q-tiles, 8 batch), block 256 (4 waves). Wave owns 16 q-rows.
// KV tile = 64. K/V fragments read directly from global (L2/L3-resident).
// Only P round-trips through per-wave LDS. No __syncthreads anywhere.
// ---------------------------------------------------------------------------
__global__ __launch_bounds__(256) void k_attn(
    const ushort* __restrict__ qt, const ushort* __restrict__ kt,
    const ushort* __restrict__ vb, ushort* __restrict__ yt)
{
    __shared__ ushort ps[4][16][72];   // per-wave P [n_local][m], stride 72 (144B)
    const int b  = blockIdx.y;
    const int n0 = blockIdx.x * 64;
    const int t    = threadIdx.x;
    const int wave = t >> 6, lane = t & 63;
    const int ln   = lane & 15, gr = lane >> 4;

    const int qrow = n0 + wave * 16 + ln;
    const short8 qf0 = *(const short8*)&qt[((size_t)b * NPIX + qrow) * 64 + gr * 8];
    const short8 qf1 = *(const short8*)&qt[((size_t)b * NPIX + qrow) * 64 + 32 + gr * 8];

    f32x4 yacc[16];
#pragma unroll
    for (int i = 0; i < 16; ++i) yacc[i] = (f32x4){0.f, 0.f, 0.f, 0.f};
    float mrun[4], lrun[4];
#pragma unroll
    for (int r = 0; r < 4; ++r) { mrun[r] = -INFINITY; lrun[r] = 0.f; }

    const ushort* ktb = kt + (size_t)b * NPIX * 64;
    const ushort* vbb = vb + (size_t)b * C2 * NPIX;
    const f32x4 zero = {0.f, 0.f, 0.f, 0.f};

    for (int m0 = 0; m0 < NPIX; m0 += 64) {
        // ---- S = Q^T K  (per wave: 16 n x 64 m) ----
        f32x4 s[4];
#pragma unroll
        for (int mt = 0; mt < 4; ++mt) {
            const ushort* kp = &ktb[(size_t)(m0 + mt * 16 + ln) * 64 + gr * 8];
            const short8 kf0 = *(const short8*)kp;
            const short8 kf1 = *(const short8*)(kp + 32);
            f32x4 sv = MFMA16(qf0, kf0, zero);
            s[mt] = MFMA16(qf1, kf1, sv);
        }
        // ---- online softmax (rows n = 4*gr + r, cols spread over 16 lanes x 4 mt) ----
#pragma unroll
        for (int r = 0; r < 4; ++r) {
            float tm = fmaxf(fmaxf(s[0][r], s[1][r]), fmaxf(s[2][r], s[3][r]));
            tm = fmaxf(tm, __shfl_xor(tm, 1));
            tm = fmaxf(tm, __shfl_xor(tm, 2));
            tm = fmaxf(tm, __shfl_xor(tm, 4));
            tm = fmaxf(tm, __shfl_xor(tm, 8));
            const float mnew = fmaxf(mrun[r], tm);
            const float rsc  = __expf(mrun[r] - mnew);
            mrun[r] = mnew;
            float rsum = 0.f;
#pragma unroll
            for (int mt = 0; mt < 4; ++mt) {
                const float p = __expf(s[mt][r] - mnew);
                rsum += p;
                ps[wave][4 * gr + r][mt * 16 + ln] = f2bf(p);
            }
            rsum += __shfl_xor(rsum, 1);
            rsum += __shfl_xor(rsum, 2);
            rsum += __shfl_xor(rsum, 4);
            rsum += __shfl_xor(rsum, 8);
            lrun[r] = lrun[r] * rsc + rsum;
#pragma unroll
            for (int ct = 0; ct < 16; ++ct) yacc[ct][r] *= rsc;
        }
        // ensure all lanes' P writes landed before cross-lane fragment reads
        asm volatile("s_waitcnt lgkmcnt(0)" ::: "memory");
        const short8 pf0 = *(const short8*)&ps[wave][ln][gr * 8];
        const short8 pf1 = *(const short8*)&ps[wave][ln][32 + gr * 8];
        // ---- Y += P V^T  (16 n x 256 c) ----
#pragma unroll
        for (int ct = 0; ct < 16; ++ct) {
            const ushort* vp = &vbb[(size_t)(ct * 16 + ln) * NPIX + m0 + gr * 8];
            const short8 vf0 = *(const short8*)vp;
            const short8 vf1 = *(const short8*)(vp + 32);
            yacc[ct] = MFMA16(pf0, vf0, yacc[ct]);
            yacc[ct] = MFMA16(pf1, vf1, yacc[ct]);
        }
    }
    // ---- epilogue: normalize, write yt[b][n][c] bf16 (transposed for proj_o) ----
    float inv[4];
#pragma unroll
    for (int r = 0; r < 4; ++r) inv[r] = 1.f / lrun[r];
#pragma unroll
    for (int ct = 0; ct < 16; ++ct) {
        const int c = ct * 16 + ln;
#pragma unroll
        for (int r = 0; r < 4; ++r) {
            const int n = n0 + wave * 16 + 4 * gr + r;
            yt[((size_t)b * NPIX + n) * C2 + c] = f2bf(yacc[ct][r] * inv[r]);
        }
    }
}

// ---------------------------------------------------------------------------
// Kernel C: out = gamma * (Wo @ y) + inputs, MFMA bf16, no LDS.
// grid (64 n-tiles, 4 j-tiles, 8 batch), block 256 (4 waves).
// Block tile: 128 j x 64 n. Wave: 128 j x 16 n. K-step 32 over 256.
// ---------------------------------------------------------------------------
__global__ __launch_bounds__(256) void k_proj_o(
    const ushort* __restrict__ yt, const float* __restrict__ Wo,
    const float* __restrict__ inp, const float* __restrict__ gamma,
    float* __restrict__ out)
{
    const int b  = blockIdx.z;
    const int j0 = blockIdx.y * 128;
    const int n0 = blockIdx.x * 64;
    const int t    = threadIdx.x;
    const int wave = t >> 6, lane = t & 63;
    const int ln   = lane & 15, gr = lane >> 4;
    const int n = n0 + wave * 16 + ln;

    f32x4 acc[8];
#pragma unroll
    for (int i = 0; i < 8; ++i) acc[i] = (f32x4){0.f, 0.f, 0.f, 0.f};

#pragma unroll
    for (int ks = 0; ks < 8; ++ks) {
        const int c0 = ks * 32;
        const short8 bf = *(const short8*)&yt[((size_t)b * NPIX + n) * C2 + c0 + gr * 8];
#pragma unroll
        for (int jt = 0; jt < 8; ++jt) {
            const int row = j0 + jt * 16 + ln;
            const float4 w0 = *(const float4*)&Wo[(size_t)row * C2 + c0 + gr * 8];
            const float4 w1 = *(const float4*)&Wo[(size_t)row * C2 + c0 + gr * 8 + 4];
            short8 af;
            af[0] = (short)f2bf(w0.x); af[1] = (short)f2bf(w0.y);
            af[2] = (short)f2bf(w0.z); af[3] = (short)f2bf(w0.w);
            af[4] = (short)f2bf(w1.x); af[5] = (short)f2bf(w1.y);
            af[6] = (short)f2bf(w1.z); af[7] = (short)f2bf(w1.w);
            acc[jt] = MFMA16(af, bf, acc[jt]);
        }
    }
    const float g = gamma[0];
#pragma unroll
    for (int jt = 0; jt < 8; ++jt) {
#pragma unroll
        for (int r = 0; r < 4; ++r) {
            const int j = j0 + jt * 16 + 4 * gr + r;
            const size_t idx = ((size_t)b * CIN + j) * NPIX + n;
            out[idx] = fmaf(g, acc[jt][r], inp[idx]);
        }
    }
}

extern "C" void kernel_launch(void* const* d_in, const int* in_sizes, int n_in,
                              void* d_out, int out_size, void* d_ws, size_t ws_size,
                              hipStream_t stream) {
    const float* inputs = (const float*)d_in[0];
    const float* Wa     = (const float*)d_in[1];
    const float* Wo     = (const float*)d_in[2];
    const float* gamma  = (const float*)d_in[3];
    float* out = (float*)d_out;

    const size_t qt_e = (size_t)BS * NPIX * 64;   // 2M ushort  -> 4 MB
    const size_t kt_e = (size_t)BS * NPIX * 64;   //            -> 4 MB
    const size_t vb_e = (size_t)BS * C2 * NPIX;   // 8M ushort  -> 16 MB
    const size_t yt_e = (size_t)BS * NPIX * C2;   //            -> 16 MB

    ushort *qt, *kt, *vb, *yt;
    if (ws_size >= (qt_e + kt_e + vb_e + yt_e) * sizeof(ushort)) {
        qt = (ushort*)d_ws;
        kt = qt + qt_e;
        vb = kt + kt_e;
        yt = vb + vb_e;
    } else {
        // vb lives in d_out (64 MB fp32 buffer; fully consumed by k_attn before
        // k_proj_o writes out). qt/kt/yt (24 MB) in d_ws. yt cannot alias d_out
        // because k_proj_o reads yt while writing out.
        vb = (ushort*)d_out;
        qt = (ushort*)d_ws;
        kt = qt + qt_e;
        yt = kt + kt_e;
    }

    k_proj_a<<<dim3(64, 3, 8), 256, 0, stream>>>(inputs, Wa, qt, kt, vb);
    k_attn  <<<dim3(64, 8),    256, 0, stream>>>(qt, kt, vb, yt);
    k_proj_o<<<dim3(64, 4, 8), 256, 0, stream>>>(yt, Wo, inputs, gamma, out);
}

// Round 3
// 413.651 us; speedup vs baseline: 4.1399x; 2.4763x over previous
//
#include <hip/hip_runtime.h>
#include <math.h>

#define BS   8
#define CIN  512
#define HC_  64
#define C2   256
#define NPIX 4096
#define WAO  384
#define TK   32           // KV tile size in k_attn
#define NT   (NPIX / TK)  // 128 KV steps

typedef __attribute__((ext_vector_type(8))) short short8;
typedef __attribute__((ext_vector_type(4))) float f32x4;

__device__ __forceinline__ ushort f2bf(float f) {
    union { float f; unsigned int u; } v; v.f = f;
    return (ushort)((v.u + 0x7FFFu + ((v.u >> 16) & 1u)) >> 16);
}

#define MFMA16(a, b, c) __builtin_amdgcn_mfma_f32_16x16x32_bf16((a), (b), (c), 0, 0, 0)

// async global->LDS, 16B per lane; LDS dest = base + lane*16 (wave-uniform base)
__device__ __forceinline__ void gl_lds16(const ushort* g, ushort* l) {
    __builtin_amdgcn_global_load_lds(
        (const __attribute__((address_space(1))) unsigned int*)g,
        (__attribute__((address_space(3))) unsigned int*)l, 16, 0, 0);
}

// ---------------------------------------------------------------------------
// Kernel W: convert Wa (384x512) and Wo (512x256) fp32 -> bf16 once.
// ---------------------------------------------------------------------------
__global__ __launch_bounds__(256) void k_cvt_w(
    const float* __restrict__ Wa, const float* __restrict__ Wo,
    ushort* __restrict__ wab, ushort* __restrict__ wob)
{
    const int i = (blockIdx.x * 256 + threadIdx.x) * 4;
    const int na = WAO * CIN;           // 196608 (divisible by 4)
    if (i < na) {
        const float4 v = *(const float4*)&Wa[i];
        ushort4 o; o.x = f2bf(v.x); o.y = f2bf(v.y); o.z = f2bf(v.z); o.w = f2bf(v.w);
        *(ushort4*)&wab[i] = o;
    } else {
        const int j = i - na;
        if (j < CIN * C2) {
            const float4 v = *(const float4*)&Wo[j];
            ushort4 o; o.x = f2bf(v.x); o.y = f2bf(v.y); o.z = f2bf(v.z); o.w = f2bf(v.w);
            *(ushort4*)&wob[j] = o;
        }
    }
}

// ---------------------------------------------------------------------------
// Kernel A: w = Wa @ inputs (1x1 conv), MFMA bf16. A-frags direct from wab.
// Writes qt[b][n][64], kt[b][m][64] (transposed), vb[b][c][m] (natural).
// grid (64 n-tiles, 3 o-tiles, 8 batch), block 256 (4 waves).
// ---------------------------------------------------------------------------
__global__ __launch_bounds__(256) void k_proj_a(
    const float* __restrict__ inp, const ushort* __restrict__ wab,
    ushort* __restrict__ qt, ushort* __restrict__ kt, ushort* __restrict__ vb)
{
    __shared__ __align__(16) ushort it[64][40];   // [n][c] bf16 staging
    const int b  = blockIdx.z;
    const int o0 = blockIdx.y * 128;
    const int n0 = blockIdx.x * 64;
    const int t    = threadIdx.x;
    const int wave = t >> 6, lane = t & 63;
    const int ln   = lane & 15, gr = lane >> 4;
    const int wn   = wave * 16;

    f32x4 acc[8];
#pragma unroll
    for (int i = 0; i < 8; ++i) acc[i] = (f32x4){0.f, 0.f, 0.f, 0.f};

    const int sc = t >> 4;          // 0..15
    const int sn = (t & 15) * 4;    // 0..60

    for (int ks = 0; ks < 16; ++ks) {
        const int c0 = ks * 32;
        __syncthreads();
#pragma unroll
        for (int q = 0; q < 2; ++q) {
            const int c = sc + 16 * q;
            const float4 v = *(const float4*)&inp[((size_t)b * CIN + c0 + c) * NPIX + n0 + sn];
            it[sn + 0][c] = f2bf(v.x); it[sn + 1][c] = f2bf(v.y);
            it[sn + 2][c] = f2bf(v.z); it[sn + 3][c] = f2bf(v.w);
        }
        __syncthreads();
        const short8 bf = *(const short8*)&it[wn + ln][gr * 8];
#pragma unroll
        for (int ot = 0; ot < 8; ++ot) {
            const int row = o0 + ot * 16 + ln;
            const short8 af = *(const short8*)&wab[(size_t)row * CIN + c0 + gr * 8];
            acc[ot] = MFMA16(af, bf, acc[ot]);
        }
    }

    const int n = n0 + wn + ln;
    if (o0 == 0) {
#pragma unroll
        for (int ot = 0; ot < 8; ++ot) {
            const ushort b0 = f2bf(acc[ot][0]), b1 = f2bf(acc[ot][1]);
            const ushort b2 = f2bf(acc[ot][2]), b3 = f2bf(acc[ot][3]);
            uint2 pk;
            pk.x = (unsigned int)b0 | ((unsigned int)b1 << 16);
            pk.y = (unsigned int)b2 | ((unsigned int)b3 << 16);
            ushort* base = (ot < 4) ? qt : kt;
            const int c4 = (ot & 3) * 16 + 4 * gr;
            *(uint2*)&base[((size_t)b * NPIX + n) * 64 + c4] = pk;
        }
    } else {
#pragma unroll
        for (int ot = 0; ot < 8; ++ot) {
            const int cb = o0 - 128 + ot * 16 + 4 * gr;
#pragma unroll
            for (int r = 0; r < 4; ++r)
                vb[((size_t)b * C2 + cb + r) * NPIX + n] = f2bf(acc[ot][r]);
        }
    }
}

// ---------------------------------------------------------------------------
// Kernel B: flash attention, bf16 MFMA, LDS-staged K/V (global_load_lds,
// double-buffered, XOR-swizzled both sides). 1D grid of 512: b = bid&7 so
// each XCD's round-robin slice serves exactly one batch (KV fits its L2).
// Block = 4 waves x 16 q-rows; KV step 32.
// LDS: K dbuf 8K + V dbuf 32K + P 5K = 45 KB -> 3 blocks/CU capacity.
// ---------------------------------------------------------------------------
__global__ __launch_bounds__(256, 3) void k_attn(
    const ushort* __restrict__ qt, const ushort* __restrict__ kt,
    const ushort* __restrict__ vb, ushort* __restrict__ yt)
{
    __shared__ __align__(16) ushort ks[2][TK][64];    // [m][c], slots swizzled ^ (m&7)
    __shared__ __align__(16) ushort vs[2][C2][TK];    // [c][m], slots swizzled ^ (c&3)
    __shared__ __align__(16) ushort ps[4][16][40];    // per-wave P [n][m], stride 80B

    const int bid = blockIdx.x;
    const int b   = bid & 7;
    const int n0  = (bid >> 3) * 64;
    const int t    = threadIdx.x;
    const int wave = t >> 6, lane = t & 63;
    const int ln   = lane & 15, gr = lane >> 4;

    const ushort* ktb = kt + (size_t)b * NPIX * 64;
    const ushort* vbb = vb + (size_t)b * C2 * NPIX;

    const int qrow = n0 + wave * 16 + ln;
    const short8 qf0 = *(const short8*)&qt[((size_t)b * NPIX + qrow) * 64 + gr * 8];
    const short8 qf1 = *(const short8*)&qt[((size_t)b * NPIX + qrow) * 64 + 32 + gr * 8];

    // staging lane roles (source slot pre-swizzled so linear LDS dest ends up
    // holding physical slot = logical slot ^ (row & mask))
    const int krow  = lane >> 3;                  // K: 8 rows/instr, 8 slots/row
    const int kslot = (lane & 7) ^ krow;
    const int vrow  = lane >> 2;                  // V: 16 rows/instr, 4 slots/row
    const int vslot = (lane & 3) ^ (vrow & 3);

    auto stage = [&](int bufi, int tile) {
        const int m0 = tile * TK;
        gl_lds16(&ktb[(size_t)(m0 + 8 * wave + krow) * 64 + kslot * 8],
                 &ks[bufi][8 * wave][0]);
#pragma unroll
        for (int jj = 0; jj < 4; ++jj) {
            const int j = 4 * wave + jj;
            gl_lds16(&vbb[(size_t)(j * 16 + vrow) * NPIX + m0 + vslot * 8],
                     &vs[bufi][j * 16][0]);
        }
    };

    f32x4 yacc[16];
#pragma unroll
    for (int i = 0; i < 16; ++i) yacc[i] = (f32x4){0.f, 0.f, 0.f, 0.f};
    float mrun[4], lrun[4];
#pragma unroll
    for (int r = 0; r < 4; ++r) { mrun[r] = -INFINITY; lrun[r] = 0.f; }
    const f32x4 zero = {0.f, 0.f, 0.f, 0.f};

    stage(0, 0);
    __syncthreads();   // compiler drains vmcnt before s_barrier

    int cur = 0;
    for (int tt = 0; tt < NT; ++tt) {
        if (tt + 1 < NT) stage(cur ^ 1, tt + 1);   // prefetch next tile
        // ---- S = Q K^T  (16 n x 32 m per wave) ----
        f32x4 s[2];
#pragma unroll
        for (int mt = 0; mt < 2; ++mt) {
            const int m = mt * 16 + ln;
            const ushort* kp = &ks[cur][m][0];
            const short8 kf0 = *(const short8*)(kp + (((gr) ^ (m & 7)) << 3));
            const short8 kf1 = *(const short8*)(kp + (((4 + gr) ^ (m & 7)) << 3));
            s[mt] = MFMA16(qf1, kf1, MFMA16(qf0, kf0, zero));
        }
        // ---- online softmax (rows n = 4*gr + r over 16 lanes x 2 mt cols) ----
#pragma unroll
        for (int r = 0; r < 4; ++r) {
            float tm = fmaxf(s[0][r], s[1][r]);
            tm = fmaxf(tm, __shfl_xor(tm, 1));
            tm = fmaxf(tm, __shfl_xor(tm, 2));
            tm = fmaxf(tm, __shfl_xor(tm, 4));
            tm = fmaxf(tm, __shfl_xor(tm, 8));
            const float mnew = fmaxf(mrun[r], tm);
            const float rsc  = __expf(mrun[r] - mnew);
            mrun[r] = mnew;
            const float p0 = __expf(s[0][r] - mnew);
            const float p1 = __expf(s[1][r] - mnew);
            ps[wave][4 * gr + r][ln]      = f2bf(p0);
            ps[wave][4 * gr + r][16 + ln] = f2bf(p1);
            float rsum = p0 + p1;
            rsum += __shfl_xor(rsum, 1);
            rsum += __shfl_xor(rsum, 2);
            rsum += __shfl_xor(rsum, 4);
            rsum += __shfl_xor(rsum, 8);
            lrun[r] = lrun[r] * rsc + rsum;
#pragma unroll
            for (int ct = 0; ct < 16; ++ct) yacc[ct][r] *= rsc;
        }
        asm volatile("s_waitcnt lgkmcnt(0)" ::: "memory");   // P writes visible
        __builtin_amdgcn_sched_barrier(0);
        const short8 pf = *(const short8*)&ps[wave][ln][gr * 8];
        // ---- Y += P V^T  (16 n x 256 c per wave) ----
#pragma unroll
        for (int ct = 0; ct < 16; ++ct) {
            const int c = ct * 16 + ln;
            const ushort* vp = &vs[cur][c][0];
            const short8 vf = *(const short8*)(vp + ((gr ^ (c & 3)) << 3));
            yacc[ct] = MFMA16(pf, vf, yacc[ct]);
        }
        __syncthreads();   // next tile staged (vmcnt drained) + buffers safe
        cur ^= 1;
    }

    float inv[4];
#pragma unroll
    for (int r = 0; r < 4; ++r) inv[r] = 1.f / lrun[r];
#pragma unroll
    for (int ct = 0; ct < 16; ++ct) {
        const int c = ct * 16 + ln;
#pragma unroll
        for (int r = 0; r < 4; ++r) {
            const int n = n0 + wave * 16 + 4 * gr + r;
            yt[((size_t)b * NPIX + n) * C2 + c] = f2bf(yacc[ct][r] * inv[r]);
        }
    }
}

// ---------------------------------------------------------------------------
// Kernel C: out = gamma * (Wo @ y) + inputs, MFMA bf16, no LDS.
// ---------------------------------------------------------------------------
__global__ __launch_bounds__(256) void k_proj_o(
    const ushort* __restrict__ yt, const ushort* __restrict__ wob,
    const float* __restrict__ inp, const float* __restrict__ gamma,
    float* __restrict__ out)
{
    const int b  = blockIdx.z;
    const int j0 = blockIdx.y * 128;
    const int n0 = blockIdx.x * 64;
    const int t    = threadIdx.x;
    const int wave = t >> 6, lane = t & 63;
    const int ln   = lane & 15, gr = lane >> 4;
    const int n = n0 + wave * 16 + ln;

    f32x4 acc[8];
#pragma unroll
    for (int i = 0; i < 8; ++i) acc[i] = (f32x4){0.f, 0.f, 0.f, 0.f};

#pragma unroll
    for (int ksi = 0; ksi < 8; ++ksi) {
        const int c0 = ksi * 32;
        const short8 bf = *(const short8*)&yt[((size_t)b * NPIX + n) * C2 + c0 + gr * 8];
#pragma unroll
        for (int jt = 0; jt < 8; ++jt) {
            const int row = j0 + jt * 16 + ln;
            const short8 af = *(const short8*)&wob[(size_t)row * C2 + c0 + gr * 8];
            acc[jt] = MFMA16(af, bf, acc[jt]);
        }
    }
    const float g = gamma[0];
#pragma unroll
    for (int jt = 0; jt < 8; ++jt) {
#pragma unroll
        for (int r = 0; r < 4; ++r) {
            const int j = j0 + jt * 16 + 4 * gr + r;
            const size_t idx = ((size_t)b * CIN + j) * NPIX + n;
            out[idx] = fmaf(g, acc[jt][r], inp[idx]);
        }
    }
}

extern "C" void kernel_launch(void* const* d_in, const int* in_sizes, int n_in,
                              void* d_out, int out_size, void* d_ws, size_t ws_size,
                              hipStream_t stream) {
    const float* inputs = (const float*)d_in[0];
    const float* Wa     = (const float*)d_in[1];
    const float* Wo     = (const float*)d_in[2];
    const float* gamma  = (const float*)d_in[3];
    float* out = (float*)d_out;

    const size_t qt_e  = (size_t)BS * NPIX * 64;    // 2M ushorts
    const size_t kt_e  = (size_t)BS * NPIX * 64;    // 2M
    const size_t vb_e  = (size_t)BS * C2 * NPIX;    // 8M
    const size_t yt_e  = (size_t)BS * NPIX * C2;    // 8M
    const size_t wab_e = (size_t)WAO * CIN;         // 196608
    const size_t wob_e = (size_t)CIN * C2;          // 131072

    ushort *qt, *kt, *vb, *yt, *wab, *wob;
    if (ws_size >= (qt_e + kt_e + vb_e + yt_e + wab_e + wob_e) * sizeof(ushort)) {
        qt  = (ushort*)d_ws;
        kt  = qt + qt_e;
        vb  = kt + kt_e;
        yt  = vb + vb_e;
        wab = yt + yt_e;
        wob = wab + wab_e;
    } else {
        // vb lives in d_out (16 MB of the 64 MB fp32 out buffer; fully consumed
        // by k_attn before k_proj_o writes out). Rest (~25 MB) in d_ws.
        vb  = (ushort*)d_out;
        qt  = (ushort*)d_ws;
        kt  = qt + qt_e;
        yt  = kt + kt_e;
        wab = yt + yt_e;
        wob = wab + wab_e;
    }

    k_cvt_w <<<dim3(320),      256, 0, stream>>>(Wa, Wo, wab, wob);
    k_proj_a<<<dim3(64, 3, 8), 256, 0, stream>>>(inputs, wab, qt, kt, vb);
    k_attn  <<<dim3(512),      256, 0, stream>>>(qt, kt, vb, yt);
    k_proj_o<<<dim3(64, 4, 8), 256, 0, stream>>>(yt, wob, inputs, gamma, out);
}

// Round 4
// 330.949 us; speedup vs baseline: 5.1744x; 1.2499x over previous
//
#include <hip/hip_runtime.h>
#include <math.h>

#define BS   8
#define CIN  512
#define HC_  64
#define C2   256
#define NPIX 4096
#define WAO  384
#define TK   32           // KV tile size in k_attn
#define NT   (NPIX / TK)  // 128 KV steps

typedef __attribute__((ext_vector_type(8))) short short8;
typedef __attribute__((ext_vector_type(4))) float f32x4;

__device__ __forceinline__ ushort f2bf(float f) {
    union { float f; unsigned int u; } v; v.f = f;
    return (ushort)((v.u + 0x7FFFu + ((v.u >> 16) & 1u)) >> 16);
}

#define MFMA16(a, b, c) __builtin_amdgcn_mfma_f32_16x16x32_bf16((a), (b), (c), 0, 0, 0)

// async global->LDS, 16B per lane; LDS dest = base + lane*16 (wave-uniform base)
__device__ __forceinline__ void gl_lds16(const ushort* g, ushort* l) {
    __builtin_amdgcn_global_load_lds(
        (const __attribute__((address_space(1))) unsigned int*)g,
        (__attribute__((address_space(3))) unsigned int*)l, 16, 0, 0);
}

// ---------------------------------------------------------------------------
// Kernel W: convert Wa (384x512) and Wo (512x256) fp32 -> bf16 once.
// ---------------------------------------------------------------------------
__global__ __launch_bounds__(256) void k_cvt_w(
    const float* __restrict__ Wa, const float* __restrict__ Wo,
    ushort* __restrict__ wab, ushort* __restrict__ wob)
{
    const int i = (blockIdx.x * 256 + threadIdx.x) * 4;
    const int na = WAO * CIN;
    if (i < na) {
        const float4 v = *(const float4*)&Wa[i];
        ushort4 o; o.x = f2bf(v.x); o.y = f2bf(v.y); o.z = f2bf(v.z); o.w = f2bf(v.w);
        *(ushort4*)&wab[i] = o;
    } else {
        const int j = i - na;
        if (j < CIN * C2) {
            const float4 v = *(const float4*)&Wo[j];
            ushort4 o; o.x = f2bf(v.x); o.y = f2bf(v.y); o.z = f2bf(v.z); o.w = f2bf(v.w);
            *(ushort4*)&wob[j] = o;
        }
    }
}

// ---------------------------------------------------------------------------
// Kernel A: w = Wa @ inputs (1x1 conv), MFMA bf16. A-frags direct from wab.
// Writes qt[b][n][64], kt[b][m][64] (transposed), vb[b][c][m] (natural).
// ---------------------------------------------------------------------------
__global__ __launch_bounds__(256) void k_proj_a(
    const float* __restrict__ inp, const ushort* __restrict__ wab,
    ushort* __restrict__ qt, ushort* __restrict__ kt, ushort* __restrict__ vb)
{
    __shared__ __align__(16) ushort it[64][40];
    const int b  = blockIdx.z;
    const int o0 = blockIdx.y * 128;
    const int n0 = blockIdx.x * 64;
    const int t    = threadIdx.x;
    const int wave = t >> 6, lane = t & 63;
    const int ln   = lane & 15, gr = lane >> 4;
    const int wn   = wave * 16;

    f32x4 acc[8];
#pragma unroll
    for (int i = 0; i < 8; ++i) acc[i] = (f32x4){0.f, 0.f, 0.f, 0.f};

    const int sc = t >> 4;
    const int sn = (t & 15) * 4;

    for (int ks = 0; ks < 16; ++ks) {
        const int c0 = ks * 32;
        __syncthreads();
#pragma unroll
        for (int q = 0; q < 2; ++q) {
            const int c = sc + 16 * q;
            const float4 v = *(const float4*)&inp[((size_t)b * CIN + c0 + c) * NPIX + n0 + sn];
            it[sn + 0][c] = f2bf(v.x); it[sn + 1][c] = f2bf(v.y);
            it[sn + 2][c] = f2bf(v.z); it[sn + 3][c] = f2bf(v.w);
        }
        __syncthreads();
        const short8 bf = *(const short8*)&it[wn + ln][gr * 8];
#pragma unroll
        for (int ot = 0; ot < 8; ++ot) {
            const int row = o0 + ot * 16 + ln;
            const short8 af = *(const short8*)&wab[(size_t)row * CIN + c0 + gr * 8];
            acc[ot] = MFMA16(af, bf, acc[ot]);
        }
    }

    const int n = n0 + wn + ln;
    if (o0 == 0) {
#pragma unroll
        for (int ot = 0; ot < 8; ++ot) {
            const ushort b0 = f2bf(acc[ot][0]), b1 = f2bf(acc[ot][1]);
            const ushort b2 = f2bf(acc[ot][2]), b3 = f2bf(acc[ot][3]);
            uint2 pk;
            pk.x = (unsigned int)b0 | ((unsigned int)b1 << 16);
            pk.y = (unsigned int)b2 | ((unsigned int)b3 << 16);
            ushort* base = (ot < 4) ? qt : kt;
            const int c4 = (ot & 3) * 16 + 4 * gr;
            *(uint2*)&base[((size_t)b * NPIX + n) * 64 + c4] = pk;
        }
    } else {
#pragma unroll
        for (int ot = 0; ot < 8; ++ot) {
            const int cb = o0 - 128 + ot * 16 + 4 * gr;
#pragma unroll
            for (int r = 0; r < 4; ++r)
                vb[((size_t)b * C2 + cb + r) * NPIX + n] = f2bf(acc[ot][r]);
        }
    }
}

// ---------------------------------------------------------------------------
// Kernel B: flash attention, bf16 MFMA. Swapped QK^T (lane owns one q-row's
// S slice), defer-max online softmax, ring-3 LDS staging with counted vmcnt
// (never drains to 0 in steady state), raw s_barrier, setprio around PV.
// grid 512 (b = bid&7 -> one batch per XCD L2), block 256 (4 waves x 16 rows).
// LDS: K ring 12K + V ring 48K + P 5K = 65 KB -> 2 blocks/CU.
// ---------------------------------------------------------------------------
__global__ __launch_bounds__(256, 2) void k_attn(
    const ushort* __restrict__ qt, const ushort* __restrict__ kt,
    const ushort* __restrict__ vb, ushort* __restrict__ yt)
{
    __shared__ __align__(16) ushort ks[3][TK][64];    // [m][c], slot ^= (m&7)
    __shared__ __align__(16) ushort vs[3][C2][TK];    // [c][m], slot ^= ((c>>1)&3)
    __shared__ __align__(16) ushort ps[4][16][40];    // per-wave P [n][m]

    const int bid = blockIdx.x;
    const int b   = bid & 7;
    const int n0  = (bid >> 3) * 64;
    const int t    = threadIdx.x;
    const int wave = t >> 6, lane = t & 63;
    const int ln   = lane & 15, gr = lane >> 4;

    const ushort* ktb = kt + (size_t)b * NPIX * 64;
    const ushort* vbb = vb + (size_t)b * C2 * NPIX;

    const int qrow = n0 + wave * 16 + ln;
    const short8 qf0 = *(const short8*)&qt[((size_t)b * NPIX + qrow) * 64 + gr * 8];
    const short8 qf1 = *(const short8*)&qt[((size_t)b * NPIX + qrow) * 64 + 32 + gr * 8];
    // drain Q loads so loop vmcnt accounting is exact
    asm volatile("s_waitcnt vmcnt(0)" ::: "memory");
    __builtin_amdgcn_sched_barrier(0);

    // precomputed swizzled read offsets (ushort units)
    const int ksl0 = ((gr ^ (ln & 7)) << 3);
    const int ksl1 = (((4 + gr) ^ (ln & 7)) << 3);
    const int vsl  = ((gr ^ ((ln >> 1) & 3)) << 3);
    // staging lane roles (source pre-swizzled; LDS dest linear)
    const int krow = lane >> 3, kslot = (lane & 7) ^ krow;
    const int vrow = lane >> 2, vslot = (lane & 3) ^ ((vrow >> 1) & 3);

    auto stage = [&](int bufi, int tile) {
        const int m0 = tile * TK;
        gl_lds16(&ktb[(size_t)(m0 + 8 * wave + krow) * 64 + kslot * 8],
                 &ks[bufi][8 * wave][0]);
#pragma unroll
        for (int jj = 0; jj < 4; ++jj) {
            const int j = 4 * wave + jj;
            gl_lds16(&vbb[(size_t)(j * 16 + vrow) * NPIX + m0 + vslot * 8],
                     &vs[bufi][j * 16][0]);
        }
    };

    f32x4 yacc[16];
#pragma unroll
    for (int i = 0; i < 16; ++i) yacc[i] = (f32x4){0.f, 0.f, 0.f, 0.f};
    float mrun = -INFINITY, lrun = 0.f;
    const f32x4 zero = {0.f, 0.f, 0.f, 0.f};

    stage(0, 0);
    stage(1, 1);
    asm volatile("s_waitcnt vmcnt(5)" ::: "memory");
    __builtin_amdgcn_s_barrier();
    __builtin_amdgcn_sched_barrier(0);

    int cur = 0;
    for (int tt = 0; tt < NT; ++tt) {
        int pre = cur + 2; if (pre >= 3) pre -= 3;
        if (tt + 2 < NT) stage(pre, tt + 2);

        // ---- S^T = K Q  : lane (gr,ln) holds S[m = mt*16+4gr+r][q-row ln] ----
        const ushort* kb = &ks[cur][0][0];
        f32x4 s[2];
#pragma unroll
        for (int mt = 0; mt < 2; ++mt) {
            const ushort* kp = kb + (mt * 16 + ln) * 64;
            const short8 kf0 = *(const short8*)(kp + ksl0);
            const short8 kf1 = *(const short8*)(kp + ksl1);
            s[mt] = MFMA16(kf1, qf1, MFMA16(kf0, qf0, zero));
        }
        // ---- online softmax, defer-max (THR=8) ----
        float tm = fmaxf(fmaxf(fmaxf(s[0][0], s[0][1]), fmaxf(s[0][2], s[0][3])),
                         fmaxf(fmaxf(s[1][0], s[1][1]), fmaxf(s[1][2], s[1][3])));
        tm = fmaxf(tm, __shfl_xor(tm, 16));
        tm = fmaxf(tm, __shfl_xor(tm, 32));
        if (__any(tm > mrun + 8.f)) {
            const float mnew = fmaxf(mrun, tm);
            const float rsc  = __expf(mrun - mnew);
            mrun = mnew;
            lrun *= rsc;
            const float r0 = __shfl(rsc, 4 * gr + 0);
            const float r1 = __shfl(rsc, 4 * gr + 1);
            const float r2 = __shfl(rsc, 4 * gr + 2);
            const float r3 = __shfl(rsc, 4 * gr + 3);
#pragma unroll
            for (int ct = 0; ct < 16; ++ct) {
                yacc[ct][0] *= r0; yacc[ct][1] *= r1;
                yacc[ct][2] *= r2; yacc[ct][3] *= r3;
            }
        }
        const float p0 = __expf(s[0][0] - mrun), p1 = __expf(s[0][1] - mrun);
        const float p2 = __expf(s[0][2] - mrun), p3 = __expf(s[0][3] - mrun);
        const float p4 = __expf(s[1][0] - mrun), p5 = __expf(s[1][1] - mrun);
        const float p6 = __expf(s[1][2] - mrun), p7 = __expf(s[1][3] - mrun);
        uint2 w0, w1;
        w0.x = (unsigned int)f2bf(p0) | ((unsigned int)f2bf(p1) << 16);
        w0.y = (unsigned int)f2bf(p2) | ((unsigned int)f2bf(p3) << 16);
        w1.x = (unsigned int)f2bf(p4) | ((unsigned int)f2bf(p5) << 16);
        w1.y = (unsigned int)f2bf(p6) | ((unsigned int)f2bf(p7) << 16);
        *(uint2*)&ps[wave][ln][4 * gr]      = w0;
        *(uint2*)&ps[wave][ln][16 + 4 * gr] = w1;
        float rsum = (p0 + p1) + (p2 + p3) + ((p4 + p5) + (p6 + p7));
        rsum += __shfl_xor(rsum, 16);
        rsum += __shfl_xor(rsum, 32);
        lrun += rsum;
        asm volatile("s_waitcnt lgkmcnt(0)" ::: "memory");
        __builtin_amdgcn_sched_barrier(0);
        const short8 pf = *(const short8*)&ps[wave][ln][gr * 8];
        // ---- Y += P V^T  (16 n x 256 c per wave) ----
        const ushort* vbase = &vs[cur][0][0];
        __builtin_amdgcn_s_setprio(1);
#pragma unroll
        for (int ct = 0; ct < 16; ++ct) {
            const short8 vf = *(const short8*)(vbase + (ct * 16 + ln) * TK + vsl);
            yacc[ct] = MFMA16(pf, vf, yacc[ct]);
        }
        __builtin_amdgcn_s_setprio(0);
        __builtin_amdgcn_sched_barrier(0);
        if (tt + 1 < NT) {
            if (tt + 2 < NT) { asm volatile("s_waitcnt vmcnt(5)" ::: "memory"); }
            else             { asm volatile("s_waitcnt vmcnt(0)" ::: "memory"); }
            __builtin_amdgcn_s_barrier();
            __builtin_amdgcn_sched_barrier(0);
        }
        cur = cur + 1; if (cur >= 3) cur -= 3;
    }

    const float il0 = 1.f / __shfl(lrun, 4 * gr + 0);
    const float il1 = 1.f / __shfl(lrun, 4 * gr + 1);
    const float il2 = 1.f / __shfl(lrun, 4 * gr + 2);
    const float il3 = 1.f / __shfl(lrun, 4 * gr + 3);
#pragma unroll
    for (int ct = 0; ct < 16; ++ct) {
        const int c = ct * 16 + ln;
        const int nb = n0 + wave * 16 + 4 * gr;
        yt[((size_t)b * NPIX + nb + 0) * C2 + c] = f2bf(yacc[ct][0] * il0);
        yt[((size_t)b * NPIX + nb + 1) * C2 + c] = f2bf(yacc[ct][1] * il1);
        yt[((size_t)b * NPIX + nb + 2) * C2 + c] = f2bf(yacc[ct][2] * il2);
        yt[((size_t)b * NPIX + nb + 3) * C2 + c] = f2bf(yacc[ct][3] * il3);
    }
}

// ---------------------------------------------------------------------------
// Kernel C: out = gamma * (Wo @ y) + inputs, MFMA bf16, no LDS.
// ---------------------------------------------------------------------------
__global__ __launch_bounds__(256) void k_proj_o(
    const ushort* __restrict__ yt, const ushort* __restrict__ wob,
    const float* __restrict__ inp, const float* __restrict__ gamma,
    float* __restrict__ out)
{
    const int b  = blockIdx.z;
    const int j0 = blockIdx.y * 128;
    const int n0 = blockIdx.x * 64;
    const int t    = threadIdx.x;
    const int wave = t >> 6, lane = t & 63;
    const int ln   = lane & 15, gr = lane >> 4;
    const int n = n0 + wave * 16 + ln;

    f32x4 acc[8];
#pragma unroll
    for (int i = 0; i < 8; ++i) acc[i] = (f32x4){0.f, 0.f, 0.f, 0.f};

#pragma unroll
    for (int ksi = 0; ksi < 8; ++ksi) {
        const int c0 = ksi * 32;
        const short8 bf = *(const short8*)&yt[((size_t)b * NPIX + n) * C2 + c0 + gr * 8];
#pragma unroll
        for (int jt = 0; jt < 8; ++jt) {
            const int row = j0 + jt * 16 + ln;
            const short8 af = *(const short8*)&wob[(size_t)row * C2 + c0 + gr * 8];
            acc[jt] = MFMA16(af, bf, acc[jt]);
        }
    }
    const float g = gamma[0];
#pragma unroll
    for (int jt = 0; jt < 8; ++jt) {
#pragma unroll
        for (int r = 0; r < 4; ++r) {
            const int j = j0 + jt * 16 + 4 * gr + r;
            const size_t idx = ((size_t)b * CIN + j) * NPIX + n;
            out[idx] = fmaf(g, acc[jt][r], inp[idx]);
        }
    }
}

extern "C" void kernel_launch(void* const* d_in, const int* in_sizes, int n_in,
                              void* d_out, int out_size, void* d_ws, size_t ws_size,
                              hipStream_t stream) {
    const float* inputs = (const float*)d_in[0];
    const float* Wa     = (const float*)d_in[1];
    const float* Wo     = (const float*)d_in[2];
    const float* gamma  = (const float*)d_in[3];
    float* out = (float*)d_out;

    const size_t qt_e  = (size_t)BS * NPIX * 64;
    const size_t kt_e  = (size_t)BS * NPIX * 64;
    const size_t vb_e  = (size_t)BS * C2 * NPIX;
    const size_t yt_e  = (size_t)BS * NPIX * C2;
    const size_t wab_e = (size_t)WAO * CIN;
    const size_t wob_e = (size_t)CIN * C2;

    ushort *qt, *kt, *vb, *yt, *wab, *wob;
    if (ws_size >= (qt_e + kt_e + vb_e + yt_e + wab_e + wob_e) * sizeof(ushort)) {
        qt  = (ushort*)d_ws;
        kt  = qt + qt_e;
        vb  = kt + kt_e;
        yt  = vb + vb_e;
        wab = yt + yt_e;
        wob = wab + wab_e;
    } else {
        vb  = (ushort*)d_out;
        qt  = (ushort*)d_ws;
        kt  = qt + qt_e;
        yt  = kt + kt_e;
        wab = yt + yt_e;
        wob = wab + wab_e;
    }

    k_cvt_w <<<dim3(320),      256, 0, stream>>>(Wa, Wo, wab, wob);
    k_proj_a<<<dim3(64, 3, 8), 256, 0, stream>>>(inputs, wab, qt, kt, vb);
    k_attn  <<<dim3(512),      256, 0, stream>>>(qt, kt, vb, yt);
    k_proj_o<<<dim3(64, 4, 8), 256, 0, stream>>>(yt, wob, inputs, gamma, out);
}